// Round 8
// baseline (381.764 us; speedup 1.0000x reference)
//
#include <hip/hip_runtime.h>
#include <stdint.h>

// ---------------------------------------------------------------------------
// Attention_18116172054662 on MI355X (gfx950)
//   L = tgt @ src^T  (2-term split-f16)
//   weight = softmax(L, axis=tgt)  -> output 1 (f32, in place in d_out)
//   out = weight @ PT^T + Q + b,  PT = W1 @ src^T,  Q = tgt @ W2^T
// R5: all-f16.  R6: algebraic restructure (PT/Q/final).  R7: swizzle (neutral
//     -> BK64 kernels are latency-starved, not LDS-bound).
// R8: MEGAKERNEL: PT + Q + logits fused into one 2048-block launch with roles
//     interleaved across block ids (fills 4 blocks/CU with mixed roles so one
//     role's barrier drains hide behind another's MFMA).  Final GEMM: BK=128
//     (16 drains instead of 32, 64 MFMA/wave/drain), 16-slot XOR swizzle.
// ---------------------------------------------------------------------------

#define B_   4
#define S_   2048
#define D_   1024
#define OUTD 1024

typedef unsigned short ushort_t;
typedef _Float16 half8 __attribute__((ext_vector_type(8)));
typedef float    f32x4 __attribute__((ext_vector_type(4)));

__device__ __forceinline__ ushort_t f2h(float f) {
    union { _Float16 h; ushort_t u; } v;
    v.h = (_Float16)f;                    // RNE
    return v.u;
}
__device__ __forceinline__ float h2f(ushort_t u) {
    union { _Float16 h; ushort_t u; } v;
    v.u = u;
    return (float)v.h;
}

// async global->LDS, 16B per lane; LDS dest = wave-uniform base + lane*16
__device__ __forceinline__ void ld16(const ushort_t* g, ushort_t* l) {
    __builtin_amdgcn_global_load_lds(
        (const __attribute__((address_space(1))) void*)g,
        (__attribute__((address_space(3))) void*)l, 16, 0, 0);
}

// --------------------------- elementwise prep ------------------------------

__global__ void k_split(const float4* __restrict__ src, const float4* __restrict__ tgt,
                        ushort4* __restrict__ sh,
                        ushort4* __restrict__ th, ushort4* __restrict__ tl)
{
    const int64_t n4 = (int64_t)B_ * S_ * D_ / 4;
    for (int64_t i = (int64_t)blockIdx.x * blockDim.x + threadIdx.x; i < n4;
         i += (int64_t)gridDim.x * blockDim.x) {
        float4 s = src[i];
        sh[i] = (ushort4){f2h(s.x), f2h(s.y), f2h(s.z), f2h(s.w)};
        float4 tv = tgt[i];
        ushort4 ht = {f2h(tv.x), f2h(tv.y), f2h(tv.z), f2h(tv.w)};
        th[i] = ht;
        tl[i] = (ushort4){f2h(tv.x - h2f(ht.x)), f2h(tv.y - h2f(ht.y)),
                          f2h(tv.z - h2f(ht.z)), f2h(tv.w - h2f(ht.w))};
    }
}

__global__ void k_wconv(const float4* __restrict__ W, ushort4* __restrict__ wb)
{
    const int64_t n4 = (int64_t)OUTD * 2 * D_ / 4;
    for (int64_t i = (int64_t)blockIdx.x * blockDim.x + threadIdx.x; i < n4;
         i += (int64_t)gridDim.x * blockDim.x) {
        float4 w = W[i];
        wb[i] = (ushort4){f2h(w.x), f2h(w.y), f2h(w.z), f2h(w.w)};
    }
}

// ----------------------- mega kernel role bodies ---------------------------

// generic NT f16 GEMM body, 128x128 tile, BK=64, f16 out (uses 16K ushort smem)
__device__ __forceinline__ void nt_body(ushort_t* smem, int t, int bx, int by,
                                        const ushort_t* __restrict__ A, int lda,
                                        const ushort_t* __restrict__ Bm, int ldb,
                                        ushort_t* __restrict__ C, int ldc, int K)
{
    ushort_t* sA = smem;            // 128*64
    ushort_t* sB = smem + 8192;     // 128*64

    int m0   = by * 128, n0 = bx * 128;
    int wave = t >> 6, lane = t & 63;
    int wr   = (wave >> 1) * 64, wc = (wave & 1) * 64;
    int l15  = lane & 15, quad = lane >> 4;
    int e7   = l15 & 7;

    f32x4 acc[4][4];
#pragma unroll
    for (int i = 0; i < 4; i++)
#pragma unroll
        for (int j = 0; j < 4; j++) acc[i][j] = (f32x4){0.f, 0.f, 0.f, 0.f};

    int srow = t >> 3;                                // 0..31
    int scol = (((t & 7) ^ (srow & 7)) * 8);          // swizzled global chunk

    const ushort_t* gA = A  + (int64_t)(m0 + srow) * lda + scol;
    const ushort_t* gB = Bm + (int64_t)(n0 + srow) * ldb + scol;
    ushort_t* lA = sA + wave * 512;
    ushort_t* lB = sB + wave * 512;

    for (int k0 = 0; k0 < K; k0 += 64) {
#pragma unroll
        for (int j = 0; j < 4; j++) {
            ld16(gA + (int64_t)(j * 32) * lda + k0, lA + j * 2048);
            ld16(gB + (int64_t)(j * 32) * ldb + k0, lB + j * 2048);
        }
        __syncthreads();
#pragma unroll
        for (int ks = 0; ks < 64; ks += 32) {
            int slot = (((ks >> 3) + quad) ^ e7) * 8;
            half8 af[4], bf[4];
#pragma unroll
            for (int i = 0; i < 4; i++)
                af[i] = *(const half8*)(&sA[(wr + i * 16 + l15) * 64 + slot]);
#pragma unroll
            for (int j = 0; j < 4; j++)
                bf[j] = *(const half8*)(&sB[(wc + j * 16 + l15) * 64 + slot]);
#pragma unroll
            for (int i = 0; i < 4; i++)
#pragma unroll
                for (int j = 0; j < 4; j++)
                    acc[i][j] = __builtin_amdgcn_mfma_f32_16x16x32_f16(af[i], bf[j], acc[i][j], 0, 0, 0);
        }
        __syncthreads();
    }

#pragma unroll
    for (int i = 0; i < 4; i++) {
        int row_base = m0 + wr + i * 16 + quad * 4;
#pragma unroll
        for (int j = 0; j < 4; j++) {
            int col = n0 + wc + j * 16 + l15;
#pragma unroll
            for (int r = 0; r < 4; r++)
                C[(int64_t)(row_base + r) * ldc + col] = f2h(acc[i][j][r]);
        }
    }
}

// logits body: L = (tgt_hi + tgt_lo) @ src^T, BK=32, fused column stats
__device__ __forceinline__ void logits_body(ushort_t* smem, float (*red_m)[128], float (*red_s)[128],
                                            int t, int bx, int by, int b,
                                            const ushort_t* __restrict__ Ah,
                                            const ushort_t* __restrict__ Al,
                                            const ushort_t* __restrict__ Bs,
                                            float* __restrict__ C,
                                            float* __restrict__ pm, float* __restrict__ ps)
{
    const int M = S_, N = S_, K = D_;
    Ah += (int64_t)b * M * K;  Al += (int64_t)b * M * K;
    Bs += (int64_t)b * N * K;
    C  += (int64_t)b * M * N;

    ushort_t* sAh = smem;            // 128*32
    ushort_t* sAl = smem + 4096;
    ushort_t* sB  = smem + 8192;

    int m0   = by * 128, n0 = bx * 128;
    int wave = t >> 6, lane = t & 63;
    int wr   = (wave >> 1) * 64, wc = (wave & 1) * 64;
    int l15  = lane & 15, quad = lane >> 4;

    f32x4 acc[4][4];
#pragma unroll
    for (int i = 0; i < 4; i++)
#pragma unroll
        for (int j = 0; j < 4; j++) acc[i][j] = (f32x4){0.f, 0.f, 0.f, 0.f};

    int srow = t >> 2;          // 0..63
    int scol = (t & 3) * 8;     // 0/8/16/24 (f16)

    const ushort_t* gAh0 = Ah + (int64_t)(m0 + srow) * K + scol;
    const ushort_t* gAh1 = gAh0 + (int64_t)64 * K;
    const ushort_t* gAl0 = Al + (int64_t)(m0 + srow) * K + scol;
    const ushort_t* gAl1 = gAl0 + (int64_t)64 * K;
    const ushort_t* gB0  = Bs + (int64_t)(n0 + srow) * K + scol;
    const ushort_t* gB1  = gB0 + (int64_t)64 * K;

    ushort_t* lAh0 = sAh + wave * 512;  ushort_t* lAh1 = sAh + 2048 + wave * 512;
    ushort_t* lAl0 = sAl + wave * 512;  ushort_t* lAl1 = sAl + 2048 + wave * 512;
    ushort_t* lB0  = sB  + wave * 512;  ushort_t* lB1  = sB  + 2048 + wave * 512;

    for (int k0 = 0; k0 < K; k0 += 32) {
        ld16(gAh0, lAh0);  ld16(gAh1, lAh1);
        ld16(gAl0, lAl0);  ld16(gAl1, lAl1);
        ld16(gB0,  lB0);   ld16(gB1,  lB1);
        gAh0 += 32; gAh1 += 32; gAl0 += 32; gAl1 += 32; gB0 += 32; gB1 += 32;
        __syncthreads();

        half8 ah[4], al[4], bf[4];
#pragma unroll
        for (int i = 0; i < 4; i++) {
            ah[i] = *(const half8*)(&sAh[(wr + i * 16 + l15) * 32 + quad * 8]);
            al[i] = *(const half8*)(&sAl[(wr + i * 16 + l15) * 32 + quad * 8]);
        }
#pragma unroll
        for (int j = 0; j < 4; j++)
            bf[j] = *(const half8*)(&sB[(wc + j * 16 + l15) * 32 + quad * 8]);
#pragma unroll
        for (int i = 0; i < 4; i++)
#pragma unroll
            for (int j = 0; j < 4; j++) {
                acc[i][j] = __builtin_amdgcn_mfma_f32_16x16x32_f16(ah[i], bf[j], acc[i][j], 0, 0, 0);
                acc[i][j] = __builtin_amdgcn_mfma_f32_16x16x32_f16(al[i], bf[j], acc[i][j], 0, 0, 0);
            }
        __syncthreads();
    }

    // C store
#pragma unroll
    for (int i = 0; i < 4; i++) {
        int row_base = m0 + wr + i * 16 + quad * 4;
#pragma unroll
        for (int j = 0; j < 4; j++) {
            int col = n0 + wc + j * 16 + l15;
#pragma unroll
            for (int r = 0; r < 4; r++)
                C[(int64_t)(row_base + r) * N + col] = acc[i][j][r];
        }
    }

    // fused partial column stats (max & sumexp over this block's 128 rows)
    int rowhalf = wave >> 1;
#pragma unroll
    for (int j = 0; j < 4; j++) {
        float m = -3.0e38f;
#pragma unroll
        for (int i = 0; i < 4; i++)
#pragma unroll
            for (int r = 0; r < 4; r++) m = fmaxf(m, acc[i][j][r]);
        float s = 0.f;
#pragma unroll
        for (int i = 0; i < 4; i++)
#pragma unroll
            for (int r = 0; r < 4; r++) s += __expf(acc[i][j][r] - m);
#pragma unroll
        for (int d = 16; d <= 32; d <<= 1) {
            float m2 = __shfl_xor(m, d, 64);
            float s2 = __shfl_xor(s, d, 64);
            float nm = fmaxf(m, m2);
            s = s * __expf(m - nm) + s2 * __expf(m2 - nm);
            m = nm;
        }
        if (lane < 16) {
            red_m[rowhalf][wc + j * 16 + l15] = m;
            red_s[rowhalf][wc + j * 16 + l15] = s;
        }
    }
    __syncthreads();
    if (t < 128) {
        float ma = red_m[0][t], mb = red_m[1][t];
        float sa = red_s[0][t], sb = red_s[1][t];
        float m = fmaxf(ma, mb);
        float s = sa * __expf(ma - m) + sb * __expf(mb - m);
        int idx = by * (B_ * S_) + b * S_ + n0 + t;
        pm[idx] = m;
        ps[idx] = s;
    }
}

// ----------------------------- mega kernel ---------------------------------
// 2048 blocks: even ids -> logits (1024), odd ids -> PT (512) then Q (512).
__launch_bounds__(256)
__global__ void k_mega(const ushort_t* __restrict__ sh, const ushort_t* __restrict__ th,
                       const ushort_t* __restrict__ tl, const ushort_t* __restrict__ wb,
                       ushort_t* __restrict__ PT, ushort_t* __restrict__ Qb,
                       float* __restrict__ C, float* __restrict__ pm, float* __restrict__ ps)
{
    __shared__ __align__(16) ushort_t smem[16384];     // 32 KB
    __shared__ float red_m[2][128], red_s[2][128];

    int id = blockIdx.x;
    int t  = threadIdx.x;

    if ((id & 1) == 0) {
        int lid = id >> 1;                             // 0..1023
        int bx = lid & 15, by = (lid >> 4) & 15, bz = lid >> 8;
        logits_body(smem, red_m, red_s, t, bx, by, bz, th, tl, sh, C, pm, ps);
    } else {
        int oid = id >> 1;                             // 0..1023
        if (oid < 512) {
            // PT[b][n][s] = sum_d W1[n][d]*src[b][s][d]  (M=1024,N=2048,K=1024)
            int bx = oid & 15, by = (oid >> 4) & 7, bz = oid >> 7;
            nt_body(smem, t, bx, by,
                    wb, 2 * D_,
                    sh + (int64_t)bz * S_ * D_, D_,
                    PT + (int64_t)bz * OUTD * S_, S_, D_);
        } else {
            // Q[b][t][n] = sum_d tgt[b][t][d]*W2[n][d]   (M=2048,N=1024,K=1024)
            int qid = oid - 512;
            int bx = qid & 7, by = (qid >> 3) & 15, bz = qid >> 7;
            nt_body(smem, t, bx, by,
                    th + (int64_t)bz * S_ * D_, D_,
                    wb + D_, 2 * D_,
                    Qb + (int64_t)bz * S_ * OUTD, OUTD, D_);
        }
    }
}

// --------------------------- column softmax --------------------------------

__global__ void k_colstats2(const float* __restrict__ pm, const float* __restrict__ ps,
                            float* __restrict__ cmax, float* __restrict__ cinv)
{
    int i = blockIdx.x * 256 + threadIdx.x;   // 8192
    float m = -3.0e38f;
#pragma unroll
    for (int c = 0; c < 16; c++) m = fmaxf(m, pm[c * (B_ * S_) + i]);
    float sum = 0.f;
#pragma unroll
    for (int c = 0; c < 16; c++) sum += ps[c * (B_ * S_) + i] * __expf(pm[c * (B_ * S_) + i] - m);
    cmax[i] = m;
    cinv[i] = 1.0f / sum;
}

__global__ void k_softmax_norm(float4* __restrict__ L, const float4* __restrict__ cmax4,
                               const float4* __restrict__ cinv4, ushort4* __restrict__ wbf)
{
    const int64_t n4 = (int64_t)B_ * S_ * S_ / 4;
    for (int64_t i = (int64_t)blockIdx.x * blockDim.x + threadIdx.x; i < n4;
         i += (int64_t)gridDim.x * blockDim.x) {
        int b  = (int)(i >> 20);
        int c4 = (int)(i & 511);
        float4 x  = L[i];
        float4 cm = cmax4[b * 512 + c4];
        float4 ci = cinv4[b * 512 + c4];
        float4 w;
        w.x = __expf(x.x - cm.x) * ci.x;
        w.y = __expf(x.y - cm.y) * ci.y;
        w.z = __expf(x.z - cm.z) * ci.z;
        w.w = __expf(x.w - cm.w) * ci.w;
        L[i] = w;
        wbf[i] = (ushort4){f2h(w.x), f2h(w.y), f2h(w.z), f2h(w.w)};
    }
}

// --------------------------- final GEMM, BK=128 ----------------------------
// out[b][t][n] = sum_s weight_f16[b][t][s]*PT[b][n][s] + Q[b][t][n] + bias[n]
// 128x128 tile, BK=128 (16 barrier drains for K=2048, 64 MFMA/wave/drain).
// LDS chunk s of row r holds global chunk s ^ (r&15)  -> reads 2-way, free.
__launch_bounds__(256)
__global__ void k_gemm_final(const ushort_t* __restrict__ Wt, const ushort_t* __restrict__ PT,
                             const ushort_t* __restrict__ Q, const float* __restrict__ bias,
                             float* __restrict__ out)
{
    const int K = S_, N = OUTD;
    int b = blockIdx.z;
    const ushort_t* A  = Wt + (int64_t)b * S_ * S_;
    const ushort_t* Bm = PT + (int64_t)b * OUTD * S_;
    const ushort_t* Qb = Q  + (int64_t)b * S_ * OUTD;
    float* Cb = out + (int64_t)b * S_ * OUTD;

    __shared__ __align__(16) ushort_t sA[128 * 128], sB[128 * 128];   // 32 KB each

    int t    = threadIdx.x;
    int m0   = blockIdx.y * 128, n0 = blockIdx.x * 128;
    int wave = t >> 6, lane = t & 63;
    int wr   = (wave >> 1) * 64, wc = (wave & 1) * 64;
    int l15  = lane & 15, quad = lane >> 4;

    f32x4 acc[4][4];
#pragma unroll
    for (int i = 0; i < 4; i++)
#pragma unroll
        for (int j = 0; j < 4; j++) acc[i][j] = (f32x4){0.f, 0.f, 0.f, 0.f};

    int srow = t >> 4;                    // 0..15 == row & 15 for staging
    int scol = ((t & 15) ^ srow) * 8;     // swizzled global source chunk

    const ushort_t* gA = A  + (int64_t)(m0 + srow) * K + scol;
    const ushort_t* gB = Bm + (int64_t)(n0 + srow) * K + scol;
    ushort_t* lA = sA + wave * 512;       // wave covers 4 rows (4*128) per pass
    ushort_t* lB = sB + wave * 512;

    for (int k0 = 0; k0 < K; k0 += 128) {
#pragma unroll
        for (int p = 0; p < 8; p++) {
            ld16(gA + (int64_t)(p * 16) * K + k0, lA + p * 2048);
            ld16(gB + (int64_t)(p * 16) * K + k0, lB + p * 2048);
        }
        __syncthreads();
#pragma unroll
        for (int ks = 0; ks < 128; ks += 32) {
            int slot = (((ks >> 3) + quad) ^ l15) * 8;
            half8 af[4], bf[4];
#pragma unroll
            for (int i = 0; i < 4; i++)
                af[i] = *(const half8*)(&sA[(wr + i * 16 + l15) * 128 + slot]);
#pragma unroll
            for (int j = 0; j < 4; j++)
                bf[j] = *(const half8*)(&sB[(wc + j * 16 + l15) * 128 + slot]);
#pragma unroll
            for (int i = 0; i < 4; i++)
#pragma unroll
                for (int j = 0; j < 4; j++)
                    acc[i][j] = __builtin_amdgcn_mfma_f32_16x16x32_f16(af[i], bf[j], acc[i][j], 0, 0, 0);
        }
        __syncthreads();
    }

#pragma unroll
    for (int i = 0; i < 4; i++) {
        int row_base = m0 + wr + i * 16 + quad * 4;
#pragma unroll
        for (int j = 0; j < 4; j++) {
            int col = n0 + wc + j * 16 + l15;
            float bv = bias[col];
#pragma unroll
            for (int r = 0; r < 4; r++) {
                int64_t idx = (int64_t)(row_base + r) * N + col;
                Cb[idx] = acc[i][j][r] + h2f(Qb[idx]) + bv;
            }
        }
    }
}

// ------------------------------- launcher ----------------------------------

extern "C" void kernel_launch(void* const* d_in, const int* in_sizes, int n_in,
                              void* d_out, int out_size, void* d_ws, size_t ws_size,
                              hipStream_t stream)
{
    const float* src  = (const float*)d_in[0];
    const float* tgt  = (const float*)d_in[1];
    const float* W    = (const float*)d_in[2];
    const float* bias = (const float*)d_in[3];

    float* out = (float*)d_out;                           // [4,2048,1024]
    float* Lw  = out + (size_t)B_ * S_ * OUTD;            // [4,2048,2048] logits -> weight

    char*  ws = (char*)d_ws;
    size_t o  = 0;
    auto take = [&](size_t bytes) -> char* {
        char* p = ws + o;
        o += (bytes + 255) & ~(size_t)255;
        return p;
    };
    const size_t ELEMS = (size_t)B_ * S_ * D_;            // 8,388,608
    ushort_t* sh   = (ushort_t*)take(ELEMS * 2);          // src f16
    ushort_t* th   = (ushort_t*)take(ELEMS * 2);          // tgt hi f16
    ushort_t* tl   = (ushort_t*)take(ELEMS * 2);          // tgt lo f16
    ushort_t* wbf  = (ushort_t*)take((size_t)B_ * S_ * S_ * 2);     // weight f16
    ushort_t* wb   = (ushort_t*)take((size_t)OUTD * 2 * D_ * 2);    // W f16 [1024,2048]
    ushort_t* PT   = (ushort_t*)take((size_t)B_ * OUTD * S_ * 2);   // W1@src^T f16
    ushort_t* Qb   = (ushort_t*)take((size_t)B_ * S_ * OUTD * 2);   // tgt@W2^T f16
    float*    pm   = (float*)take(16 * (size_t)B_ * S_ * 4);
    float*    ps   = (float*)take(16 * (size_t)B_ * S_ * 4);
    float*    cmax = (float*)take((size_t)B_ * S_ * 4);
    float*    cinv = (float*)take((size_t)B_ * S_ * 4);
    (void)ws_size; (void)in_sizes; (void)n_in; (void)out_size;

    k_split<<<dim3(2048), dim3(256), 0, stream>>>((const float4*)src, (const float4*)tgt,
                                                  (ushort4*)sh, (ushort4*)th, (ushort4*)tl);
    k_wconv<<<dim3(512), dim3(256), 0, stream>>>((const float4*)W, (ushort4*)wb);

    // PT + Q + logits fused: 2048 blocks, roles interleaved by block id
    k_mega<<<dim3(2048), dim3(256), 0, stream>>>(sh, th, tl, wb, PT, Qb, Lw, pm, ps);

    k_colstats2<<<dim3(32), dim3(256), 0, stream>>>(pm, ps, cmax, cinv);
    k_softmax_norm<<<dim3(2048), dim3(256), 0, stream>>>((float4*)Lw, (const float4*)cmax,
                                                         (const float4*)cinv, (ushort4*)wbf);

    k_gemm_final<<<dim3(8, 16, 4), dim3(256), 0, stream>>>(wbf, PT, Qb, bias, out);
}